// Round 2
// baseline (546.355 us; speedup 1.0000x reference)
//
#include <hip/hip_runtime.h>

// Jacobi pseudo-timestepping of -div(exp(u) grad p) = f on a 1024x1024 grid.
// p_new = (eu*p_xp + eu_xm*p_xm + eu*p_yp + eu_ym*p_ym + h^2 f) / denom
// denom = 2*eu + eu_xm + eu_ym;  BC: p[:,0]=i*h, p[:,N-1]=1-i*h; edge-replicate in x.
//
// Strategy: precompute folded coefficients once (A,Bx,By,D all divided by denom),
// fold step 1 (p0=0 -> p1=D interior) into the precompute kernel, then 99 stencil
// sweeps ping-ponging between a ws buffer and d_out.

#define GN 1024
constexpr int NN = GN * GN;

__global__ __launch_bounds__(256) void gw_pre(const float* __restrict__ u,
                                              const float* __restrict__ f,
                                              float* __restrict__ A,
                                              float* __restrict__ Bx,
                                              float* __restrict__ By,
                                              float* __restrict__ D,
                                              float* __restrict__ p1) {
    int idx = blockIdx.x * 256 + threadIdx.x;
    int i = idx >> 10;
    int j = idx & (GN - 1);
    const float h = 1.0f / (GN - 1);

    float e   = expf(u[idx]);
    float exm = (i > 0) ? expf(u[idx - GN]) : e;   // edge-replicate row 0
    float eym = (j > 0) ? expf(u[idx - 1])  : e;   // edge-replicate col 0
    float den = 2.0f * e + exm + eym;
    float rd  = 1.0f / den;

    A[idx]  = e * rd;
    Bx[idx] = exm * rd;
    By[idx] = eym * rd;
    float d = h * h * f[idx] * rd;
    D[idx]  = d;

    // step 1 from p0 = 0: interior is just D, edges are the Dirichlet BC
    float p;
    if (j == 0)            p = i * h;
    else if (j == GN - 1)  p = 1.0f - i * h;
    else                   p = d;
    p1[idx] = p;
}

__global__ __launch_bounds__(256) void gw_step(const float* __restrict__ pin,
                                               float* __restrict__ pout,
                                               const float* __restrict__ A,
                                               const float* __restrict__ Bx,
                                               const float* __restrict__ By,
                                               const float* __restrict__ D) {
    int idx = blockIdx.x * 256 + threadIdx.x;
    int i = idx >> 10;
    int j = idx & (GN - 1);
    const float h = 1.0f / (GN - 1);

    if (j == 0)       { pout[idx] = i * h;        return; }
    if (j == GN - 1)  { pout[idx] = 1.0f - i * h; return; }

    float pxp = pin[(i < GN - 1) ? idx + GN : idx];  // edge-replicate in x
    float pxm = pin[(i > 0)      ? idx - GN : idx];
    float pyp = pin[idx + 1];
    float pym = pin[idx - 1];

    float r = fmaf(A[idx], pxp + pyp, D[idx]);
    r = fmaf(Bx[idx], pxm, r);
    r = fmaf(By[idx], pym, r);
    pout[idx] = r;
}

extern "C" void kernel_launch(void* const* d_in, const int* in_sizes, int n_in,
                              void* d_out, int out_size, void* d_ws, size_t ws_size,
                              hipStream_t stream) {
    const float* u = (const float*)d_in[0];
    const float* f = (const float*)d_in[1];
    // d_in[2] is time_steps == 100 (compile-time constant in the reference harness)
    float* out = (float*)d_out;

    float* ws = (float*)d_ws;
    float* A  = ws;
    float* Bx = ws + (size_t)NN;
    float* By = ws + (size_t)2 * NN;
    float* D  = ws + (size_t)3 * NN;
    float* pA = ws + (size_t)4 * NN;

    dim3 grid(NN / 256), block(256);

    // precompute coefficients + step 1 (p1 into pA)
    gw_pre<<<grid, block, 0, stream>>>(u, f, A, Bx, By, D, pA);

    // steps 2..100: 99 launches; odd count means the last write lands in d_out
    float* src = pA;
    float* dst = out;
    for (int k = 2; k <= 100; ++k) {
        gw_step<<<grid, block, 0, stream>>>(src, dst, A, Bx, By, D);
        float* t = src; src = dst; dst = t;
    }
}

// Round 4
// 399.286 us; speedup vs baseline: 1.3683x; 1.3683x over previous
//
#include <hip/hip_runtime.h>

// Jacobi pseudo-timestepping of -div(exp(u) grad p) = f on a 1024x1024 grid,
// temporally blocked: K=4 steps fused per kernel in LDS.
//
// p_new = A*(p_xp + p_yp) + Bx*p_xm + By*p_ym + D
//   A = eu/den, Bx = eu_xm/den, By = eu_ym/den, D = h^2 f/den, den = 2eu+eu_xm+eu_ym
// BC: p[:,0] = i*h, p[:,N-1] = 1-i*h;  edge-replicate in x (rows).
//
// Each block: stage p (T+2K)^2 with halo K (clamped), coefficients (T+2K-2)^2
// as packed float4, then K shrinking sweeps in LDS ping-pong buffers; write T^2.
// Halo cells outside the grid evaluate the stencil at their CLAMPED position,
// which keeps them exact mirror copies of the edge rows (edge-replicate in x).

#define GN 1024
#define TT 32
constexpr int NN = GN * GN;

__global__ __launch_bounds__(256) void gw_pre(const float* __restrict__ u,
                                              const float* __restrict__ f,
                                              float4* __restrict__ C4,
                                              float* __restrict__ p1) {
    int idx = blockIdx.x * 256 + threadIdx.x;
    int i = idx >> 10;
    int j = idx & (GN - 1);
    const float h = 1.0f / (GN - 1);

    float e   = expf(u[idx]);
    float exm = (i > 0) ? expf(u[idx - GN]) : e;   // edge-replicate row 0
    float eym = (j > 0) ? expf(u[idx - 1])  : e;   // edge-replicate col 0
    float rd  = 1.0f / (2.0f * e + exm + eym);

    float d = h * h * f[idx] * rd;
    C4[idx] = make_float4(e * rd, exm * rd, eym * rd, d);

    // step 1 from p0 = 0: interior is just D, BC columns overridden
    float p;
    if (j == 0)            p = i * h;
    else if (j == GN - 1)  p = 1.0f - i * h;
    else                   p = d;
    p1[idx] = p;
}

template <int K>
__global__ __launch_bounds__(256) void gw_fused(const float* __restrict__ pin,
                                                float* __restrict__ pout,
                                                const float4* __restrict__ C4) {
    constexpr int S  = TT + 2 * K;       // staged p tile (40 for K=4)
    constexpr int CS = TT + 2 * K - 2;   // coefficient tile (38 for K=4)

    __shared__ float  buf[2][S * S];
    __shared__ float4 coef[CS * CS];

    const int tid = threadIdx.x;
    const int ti  = (blockIdx.x >> 5) * TT;   // 32x32 grid of tiles
    const int tj  = (blockIdx.x & 31) * TT;
    const float h = 1.0f / (GN - 1);

    // stage p with halo K (clamped = edge replicate; BC columns already hold BC)
    for (int t = tid; t < S * S; t += 256) {
        int li = t / S, lj = t % S;
        int gi = min(max(ti - K + li, 0), GN - 1);
        int gj = min(max(tj - K + lj, 0), GN - 1);
        buf[0][t] = pin[gi * GN + gj];
    }
    // stage coefficients with halo K-1 (clamped)
    for (int t = tid; t < CS * CS; t += 256) {
        int li = t / CS, lj = t % CS;
        int gi = min(max(ti - (K - 1) + li, 0), GN - 1);
        int gj = min(max(tj - (K - 1) + lj, 0), GN - 1);
        coef[t] = C4[gi * GN + gj];
    }
    __syncthreads();

    const bool edge = (ti == 0) | (tj == 0) | (ti + TT == GN) | (tj + TT == GN);

    int cur = 0;
    #pragma unroll
    for (int s = 1; s <= K; ++s) {
        const int R = S - 2 * s;   // constexpr per unrolled iteration
        const float* __restrict__ bp = buf[cur];
        float* __restrict__ bo = buf[cur ^ 1];
        for (int t = tid; t < R * R; t += 256) {
            int li = s + t / R, lj = s + t % R;
            float val;
            if (!edge) {
                float4 c  = coef[(li - 1) * CS + (lj - 1)];
                float pxm = bp[(li - 1) * S + lj];
                float pxp = bp[(li + 1) * S + lj];
                float pym = bp[li * S + lj - 1];
                float pyp = bp[li * S + lj + 1];
                val = fmaf(c.x, pxp + pyp, c.w);
                val = fmaf(c.y, pxm, val);
                val = fmaf(c.z, pym, val);
            } else {
                int gi = ti - K + li, gj = tj - K + lj;
                int ci = min(max(gi, 0), GN - 1);
                int cj = min(max(gj, 0), GN - 1);
                if (cj == 0)            val = ci * h;
                else if (cj == GN - 1)  val = 1.0f - ci * h;
                else {
                    int lic = li + (ci - gi), ljc = lj + (cj - gj);
                    float4 c  = coef[(lic - 1) * CS + (ljc - 1)];
                    float pxm = bp[(lic - 1) * S + ljc];
                    float pxp = bp[(lic + 1) * S + ljc];
                    float pym = bp[lic * S + ljc - 1];
                    float pyp = bp[lic * S + ljc + 1];
                    val = fmaf(c.x, pxp + pyp, c.w);
                    val = fmaf(c.y, pxm, val);
                    val = fmaf(c.z, pym, val);
                }
            }
            bo[li * S + lj] = val;
        }
        cur ^= 1;
        __syncthreads();
    }

    // write the T x T interior
    for (int t = tid; t < TT * TT; t += 256) {
        int li = K + (t >> 5), lj = K + (t & 31);
        int gi = ti + (t >> 5), gj = tj + (t & 31);
        pout[gi * GN + gj] = buf[cur][li * S + lj];
    }
}

extern "C" void kernel_launch(void* const* d_in, const int* in_sizes, int n_in,
                              void* d_out, int out_size, void* d_ws, size_t ws_size,
                              hipStream_t stream) {
    const float* u = (const float*)d_in[0];
    const float* f = (const float*)d_in[1];
    float* out = (float*)d_out;

    float*  ws = (float*)d_ws;
    float4* C4 = (float4*)ws;                       // 16 MB packed coefficients
    float*  pA = ws + (size_t)4 * NN;               // 4 MB ping buffer

    dim3 gridE(NN / 256), block(256);
    dim3 gridT(1024);  // 32x32 tiles of 32x32

    // step 1 (+ coefficient pack)
    gw_pre<<<gridE, block, 0, stream>>>(u, f, C4, pA);

    // steps 2..97: 24 fused K=4 kernels; steps 98..100: one K=3 kernel.
    // 25 fused launches, odd count -> final lands in d_out.
    float* src = pA;
    float* dst = out;
    for (int k = 0; k < 24; ++k) {
        gw_fused<4><<<gridT, block, 0, stream>>>(src, dst, C4);
        float* t = src; src = dst; dst = t;
    }
    gw_fused<3><<<gridT, block, 0, stream>>>(src, dst, C4);
}